// Round 1
// baseline (126.746 us; speedup 1.0000x reference)
//
#include <hip/hip_runtime.h>

#define NN 10000
#define KK 64
#define CC 128
#define OUTOFF (NN * CC)   // 1,280,000 floats: imag half of d_out

__device__ __forceinline__ float4 f4fma(float s, float4 v, float4 a) {
    a.x += s * v.x; a.y += s * v.y; a.z += s * v.z; a.w += s * v.w;
    return a;
}

// ---------------- Phase A: partial U,V = split-K of Q^T X ----------------
// part layout: [block][m(0=U,1=V)][k(64)][c(128)] floats (16384 per block)
__global__ __launch_bounds__(512) void kA(const float* __restrict__ re,
                                          const float* __restrict__ im,
                                          const float* __restrict__ Qr,
                                          const float* __restrict__ Qi,
                                          float* __restrict__ part, int nA)
{
    __shared__ float4 sQr[16][16];   // 16 rows x 64 floats
    __shared__ float4 sQi[16][16];
    __shared__ float4 sRe[16][32];   // 16 rows x 128 floats
    __shared__ float4 sIm[16][32];

    const int t  = threadIdx.x;
    const int kt = t & 15;   // k0 = 4*kt
    const int ct = t >> 4;   // c0 = 4*ct  (0..31)

    float aU[4][4], aV[4][4];
#pragma unroll
    for (int a = 0; a < 4; ++a)
#pragma unroll
        for (int b = 0; b < 4; ++b) { aU[a][b] = 0.f; aV[a][b] = 0.f; }

    for (int cb = blockIdx.x; cb < 625; cb += nA) {   // 625*16 == 10000 exactly
        const int n0 = cb * 16;
        for (int i = t; i < 1536; i += 512) {
            if (i < 256) {
                int row = i >> 4, q = i & 15;
                sQr[row][q] = ((const float4*)(Qr + (size_t)(n0 + row) * KK))[q];
            } else if (i < 512) {
                int j = i - 256, row = j >> 4, q = j & 15;
                sQi[row][q] = ((const float4*)(Qi + (size_t)(n0 + row) * KK))[q];
            } else if (i < 1024) {
                int j = i - 512, row = j >> 5, q = j & 31;
                sRe[row][q] = ((const float4*)(re + (size_t)(n0 + row) * CC))[q];
            } else {
                int j = i - 1024, row = j >> 5, q = j & 31;
                sIm[row][q] = ((const float4*)(im + (size_t)(n0 + row) * CC))[q];
            }
        }
        __syncthreads();
#pragma unroll 4
        for (int r = 0; r < 16; ++r) {
            float4 q_r = sQr[r][kt];
            float4 q_i = sQi[r][kt];
            float4 x_r = sRe[r][ct];
            float4 x_i = sIm[r][ct];
            float qr[4] = {q_r.x, q_r.y, q_r.z, q_r.w};
            float qi[4] = {q_i.x, q_i.y, q_i.z, q_i.w};
            float xr[4] = {x_r.x, x_r.y, x_r.z, x_r.w};
            float xi[4] = {x_i.x, x_i.y, x_i.z, x_i.w};
#pragma unroll
            for (int a = 0; a < 4; ++a)
#pragma unroll
                for (int b = 0; b < 4; ++b) {
                    aU[a][b] += qr[a] * xr[b] + qi[a] * xi[b];
                    aV[a][b] += qi[a] * xr[b] - qr[a] * xi[b];
                }
        }
        __syncthreads();
    }
    float* base = part + (size_t)blockIdx.x * 16384;
    const int k0 = kt * 4, c0 = ct * 4;
#pragma unroll
    for (int a = 0; a < 4; ++a) {
        *(float4*)(base + (k0 + a) * CC + c0)        = make_float4(aU[a][0], aU[a][1], aU[a][2], aU[a][3]);
        *(float4*)(base + 8192 + (k0 + a) * CC + c0) = make_float4(aV[a][0], aV[a][1], aV[a][2], aV[a][3]);
    }
}

// ---------------- Phase R: reduce partials -> UV[2][64][128] ----------------
__global__ __launch_bounds__(256) void kR(const float* __restrict__ part,
                                          float* __restrict__ UV, int nA)
{
    __shared__ float red[256];
    const int t  = threadIdx.x;
    const int e0 = blockIdx.x * 32;   // grid 512 covers 16384 elements
    const int ei = t & 31, sl = t >> 5;
    float s = 0.f;
    for (int b = sl; b < nA; b += 8)
        s += part[(size_t)b * 16384 + e0 + ei];
    red[t] = s;
    __syncthreads();
    if (t < 32) {
        float tot = 0.f;
#pragma unroll
        for (int q = 0; q < 8; ++q) tot += red[q * 32 + t];
        UV[e0 + t] = tot;
    }
}

// ---------------- Phase B: UVW = diag(TT) * (U|V) @ W ----------------
__global__ __launch_bounds__(256) void kB(const float* __restrict__ UV,
                                          const float* __restrict__ Ritz,
                                          const int* __restrict__ ldp,
                                          const float* __restrict__ W,
                                          float* __restrict__ UVW)
{
    __shared__ float rowU[128], rowV[128];
    const int k = blockIdx.x, t = threadIdx.x;
    if (t < 128) rowU[t] = UV[k * 128 + t];
    else         rowV[t - 128] = UV[8192 + k * 128 + (t - 128)];
    __syncthreads();
    const int m = t >> 7, c = t & 127;
    const float* row = m ? rowV : rowU;
    float acc = 0.f;
#pragma unroll 8
    for (int cp = 0; cp < 128; ++cp)
        acc += row[cp] * W[cp * 128 + c];
    const int ld = *ldp;
    const float rz = Ritz[k];
    float tt = 1.f;
    for (int i = 0; i < ld; ++i) tt *= rz;
    UVW[m * 8192 + k * 128 + c] = tt * acc;
}

// ---------------- Phase C: res = Q @ UVW, fused masked-ReLU epilogue ----------------
__global__ __launch_bounds__(256) void kC(const float* __restrict__ re,
                                          const float* __restrict__ im,
                                          const float* __restrict__ Qr,
                                          const float* __restrict__ Qi,
                                          const float* __restrict__ UVW,
                                          float* __restrict__ out)
{
    __shared__ float4 sUW[64][32];   // 32 KB
    __shared__ float4 sVW[64][32];   // 32 KB
    const int t = threadIdx.x;
    {
        const float4* g = (const float4*)UVW;
        float4* s0 = &sUW[0][0];
        float4* s1 = &sVW[0][0];
        for (int i = t; i < 2048; i += 256) s0[i] = g[i];
        for (int i = t; i < 2048; i += 256) s1[i] = g[2048 + i];
    }
    __syncthreads();
    const int ct = t & 15;   // cols 4*ct..+3 and 64+4*ct..+3
    const int rp = t >> 4;   // row pair within 32-row chunk

    for (int cb = blockIdx.x; cb < 313; cb += 256) {
        const int na = cb * 32 + rp * 2;
        if (na >= NN) continue;          // N%32==16: pairs are all-valid or all-invalid
        const int nb = na + 1;
        const float4* qra = (const float4*)(Qr + (size_t)na * KK);
        const float4* qia = (const float4*)(Qi + (size_t)na * KK);
        const float4* qrb = (const float4*)(Qr + (size_t)nb * KK);
        const float4* qib = (const float4*)(Qi + (size_t)nb * KK);

        float4 z = make_float4(0.f, 0.f, 0.f, 0.f);
        float4 aR0a = z, aR1a = z, aI0a = z, aI1a = z;
        float4 aR0b = z, aR1b = z, aI0b = z, aI1b = z;

#pragma unroll 4
        for (int k4 = 0; k4 < 16; ++k4) {
            float4 QRa = qra[k4], QIa = qia[k4];
            float4 QRb = qrb[k4], QIb = qib[k4];
            float ar[4] = {QRa.x, QRa.y, QRa.z, QRa.w};
            float ai[4] = {QIa.x, QIa.y, QIa.z, QIa.w};
            float br[4] = {QRb.x, QRb.y, QRb.z, QRb.w};
            float bi[4] = {QIb.x, QIb.y, QIb.z, QIb.w};
#pragma unroll
            for (int j = 0; j < 4; ++j) {
                const int k = k4 * 4 + j;
                float4 uw0 = sUW[k][ct], uw1 = sUW[k][16 + ct];
                float4 vw0 = sVW[k][ct], vw1 = sVW[k][16 + ct];
                aR0a = f4fma(ar[j], uw0, aR0a); aR0a = f4fma(ai[j], vw0, aR0a);
                aR1a = f4fma(ar[j], uw1, aR1a); aR1a = f4fma(ai[j], vw1, aR1a);
                aI0a = f4fma(ai[j], uw0, aI0a); aI0a = f4fma(-ar[j], vw0, aI0a);
                aI1a = f4fma(ai[j], uw1, aI1a); aI1a = f4fma(-ar[j], vw1, aI1a);
                aR0b = f4fma(br[j], uw0, aR0b); aR0b = f4fma(bi[j], vw0, aR0b);
                aR1b = f4fma(br[j], uw1, aR1b); aR1b = f4fma(bi[j], vw1, aR1b);
                aI0b = f4fma(bi[j], uw0, aI0b); aI0b = f4fma(-br[j], vw0, aI0b);
                aI1b = f4fma(bi[j], uw1, aI1b); aI1b = f4fma(-br[j], vw1, aI1b);
            }
        }
        const int c0 = ct * 4;
#pragma unroll
        for (int half = 0; half < 2; ++half) {
            const int cc = c0 + half * 64;
            const float4 aRa = half ? aR1a : aR0a;
            const float4 aIa = half ? aI1a : aI0a;
            const float4 aRb = half ? aR1b : aR0b;
            const float4 aIb = half ? aI1b : aI0b;

            float4 rin = *(const float4*)(re + (size_t)na * CC + cc);
            float4 iin = *(const float4*)(im + (size_t)na * CC + cc);
            float4 orr, oii;
            orr.x = rin.x + (aRa.x >= 0.f ? aRa.x : 0.f); oii.x = iin.x + (aRa.x >= 0.f ? aIa.x : 0.f);
            orr.y = rin.y + (aRa.y >= 0.f ? aRa.y : 0.f); oii.y = iin.y + (aRa.y >= 0.f ? aIa.y : 0.f);
            orr.z = rin.z + (aRa.z >= 0.f ? aRa.z : 0.f); oii.z = iin.z + (aRa.z >= 0.f ? aIa.z : 0.f);
            orr.w = rin.w + (aRa.w >= 0.f ? aRa.w : 0.f); oii.w = iin.w + (aRa.w >= 0.f ? aIa.w : 0.f);
            *(float4*)(out + (size_t)na * CC + cc)          = orr;
            *(float4*)(out + OUTOFF + (size_t)na * CC + cc) = oii;

            rin = *(const float4*)(re + (size_t)nb * CC + cc);
            iin = *(const float4*)(im + (size_t)nb * CC + cc);
            orr.x = rin.x + (aRb.x >= 0.f ? aRb.x : 0.f); oii.x = iin.x + (aRb.x >= 0.f ? aIb.x : 0.f);
            orr.y = rin.y + (aRb.y >= 0.f ? aRb.y : 0.f); oii.y = iin.y + (aRb.y >= 0.f ? aIb.y : 0.f);
            orr.z = rin.z + (aRb.z >= 0.f ? aRb.z : 0.f); oii.z = iin.z + (aRb.z >= 0.f ? aIb.z : 0.f);
            orr.w = rin.w + (aRb.w >= 0.f ? aRb.w : 0.f); oii.w = iin.w + (aRb.w >= 0.f ? aIb.w : 0.f);
            *(float4*)(out + (size_t)nb * CC + cc)          = orr;
            *(float4*)(out + OUTOFF + (size_t)nb * CC + cc) = oii;
        }
    }
}

extern "C" void kernel_launch(void* const* d_in, const int* in_sizes, int n_in,
                              void* d_out, int out_size, void* d_ws, size_t ws_size,
                              hipStream_t stream) {
    const float* re   = (const float*)d_in[0];
    const float* im   = (const float*)d_in[1];
    const float* Qr   = (const float*)d_in[2];
    const float* Qi   = (const float*)d_in[3];
    const float* Ritz = (const float*)d_in[4];
    const float* W    = (const float*)d_in[5];
    const int*   ldp  = (const int*)d_in[6];
    float* out = (float*)d_out;
    float* ws  = (float*)d_ws;

    // ws budget: nA partial blocks of 64 KB + UV (64 KB) + UVW (64 KB)
    long avail = ((long)ws_size - 131072L) / 65536L;
    int nA = (int)(avail < 1 ? 1 : (avail > 256 ? 256 : avail));

    float* part = ws;
    float* UV   = ws + (size_t)nA * 16384;
    float* UVW  = UV + 16384;

    kA<<<nA, 512, 0, stream>>>(re, im, Qr, Qi, part, nA);
    kR<<<512, 256, 0, stream>>>(part, UV, nA);
    kB<<<64, 256, 0, stream>>>(UV, Ritz, ldp, W, UVW);
    kC<<<256, 256, 0, stream>>>(re, im, Qr, Qi, UVW, out);
}